// Round 1
// baseline (303.166 us; speedup 1.0000x reference)
//
#include <hip/hip_runtime.h>

typedef __attribute__((ext_vector_type(8))) short short8;
typedef __attribute__((ext_vector_type(4))) short short4v;
typedef __attribute__((ext_vector_type(4))) float float4v;
typedef __attribute__((ext_vector_type(8))) __bf16 bf16x8;

// LDS layout (bytes):
//   region A  [0, 57344)        : XT bf16[49][512] (swizzled) during GEMMs; VT[8][64][56] after V
//   PQ        [57344, 107520)   : P_q bf16 flat s*128+dd*2 (swizzled)   (50176 B)
//   PK        [107520, 157696)  : P_k same                              (50176 B)
//   BIAS      [157696, 163104)  : bias_table f32 [169][8]               (5408 B)
#define LDS_PQ 57344
#define LDS_PK 107520
#define LDS_BIAS 157696
#define LDS_TOTAL 163104

__device__ __forceinline__ unsigned short f2bf(float f) {
  unsigned u = __float_as_uint(f);
  u += 0x7FFFu + ((u >> 16) & 1u);   // RNE
  return (unsigned short)(u >> 16);
}

// ---- kernel 1: convert q_w/k_w/v_w fp32 -> bf16 into workspace ----
__global__ void wconv_kernel(const float* __restrict__ qw, const float* __restrict__ kw,
                             const float* __restrict__ vw, short* __restrict__ out) {
  int g = blockIdx.x >> 8;  // 0:q 1:k 2:v
  const float* src = (g == 0) ? qw : (g == 1) ? kw : vw;
  int off = ((blockIdx.x & 255) * 256 + threadIdx.x) * 4;
  float4v v = *(const float4v*)(src + off);
  short4v o;
  o.x = (short)f2bf(v.x); o.y = (short)f2bf(v.y);
  o.z = (short)f2bf(v.z); o.w = (short)f2bf(v.w);
  *(short4v*)(out + g * 262144 + off) = o;
}

// ---- kernel 2: fused windowed attention, one workgroup per (b, window) ----
__global__ __launch_bounds__(512, 2) void wattn_kernel(
    const float* __restrict__ x, const short* __restrict__ wcvt,
    const float* __restrict__ qb, const float* __restrict__ kb, const float* __restrict__ vb,
    const float* __restrict__ btab, float* __restrict__ out) {
  __shared__ __align__(16) char sm[LDS_TOTAL];
  const int tid  = threadIdx.x;
  const int lane = tid & 63;
  const int wave = tid >> 6;       // 8 waves; wave == head in attention phase
  const int bwi  = blockIdx.x;     // b*64 + wi
  const int bb   = bwi >> 6, wi = bwi & 63;
  const int l15  = lane & 15;
  const int l4   = lane >> 4;
  const int ig   = l4 * 4;

  // stage bias table (f32, 169*8)
  for (int i = tid; i < 169 * 8; i += 512)
    *(float*)(sm + LDS_BIAS + i * 4) = btab[i];

  // stage x tile -> XT bf16 [49][512], row-XOR swizzle
  {
    const float* xb = x + (size_t)bb * (3136 * 512);
    const int whi = (wi >> 3) * 7, wlo = (wi & 7) * 7;
    for (int idx = tid; idx < 49 * 128; idx += 512) {
      int t = idx >> 7, c4 = idx & 127;
      int yt = (t * 37) >> 8, xt = t - yt * 7;
      int l = (whi + yt) * 56 + wlo + xt;
      float4v v = *(const float4v*)(xb + l * 512 + c4 * 4);
      short4v o;
      o.x = (short)f2bf(v.x); o.y = (short)f2bf(v.y);
      o.z = (short)f2bf(v.z); o.w = (short)f2bf(v.w);
      int byte = t * 1024 + c4 * 8;
      *(short4v*)(sm + (byte ^ ((t & 7) << 4))) = o;
    }
  }
  __syncthreads();

  const int wcol = wave * 64;

  // ---- three projection GEMMs: P = XT @ W^T + b ----
  for (int g = 0; g < 3; ++g) {
    const short* wt = wcvt + g * 262144;
    const float* bias = (g == 0) ? qb : (g == 1) ? kb : vb;
    float4v acc[4][4];
#pragma unroll
    for (int m = 0; m < 4; ++m)
#pragma unroll
      for (int n = 0; n < 4; ++n) acc[m][n] = (float4v)0.f;

    for (int kk = 0; kk < 16; ++kk) {
      const int k0 = kk * 32 + l4 * 8;
      bf16x8 a[4], b[4];
#pragma unroll
      for (int m = 0; m < 4; ++m) {
        int row = m * 16 + l15;
        if (row < 49) {
          int byte = row * 1024 + k0 * 2;
          a[m] = __builtin_bit_cast(bf16x8, *(const short8*)(sm + (byte ^ ((row & 7) << 4))));
        } else {
          a[m] = __builtin_bit_cast(bf16x8, (short8)0);
        }
      }
#pragma unroll
      for (int n = 0; n < 4; ++n) {
        int o = wcol + n * 16 + l15;
        b[n] = __builtin_bit_cast(bf16x8, *(const short8*)(wt + o * 512 + k0));
      }
#pragma unroll
      for (int m = 0; m < 4; ++m)
#pragma unroll
        for (int n = 0; n < 4; ++n)
          acc[m][n] = __builtin_amdgcn_mfma_f32_16x16x32_bf16(a[m], b[n], acc[m][n], 0, 0, 0);
    }

    if (g < 2) {
      const int base = (g == 0) ? LDS_PQ : LDS_PK;
#pragma unroll
      for (int n = 0; n < 4; ++n) {
        int o = wcol + n * 16 + l15;
        float bv = bias[o];
#pragma unroll
        for (int m = 0; m < 4; ++m)
#pragma unroll
          for (int r = 0; r < 4; ++r) {
            int t = m * 16 + ig + r;
            if (t < 49) {
              int s = t * 8 + (o >> 6);
              int flat = s * 128 + (o & 63) * 2;
              *(unsigned short*)(sm + base + (flat ^ ((s & 7) << 4))) = f2bf(acc[m][n][r] + bv);
            }
          }
      }
    } else {
      __syncthreads();  // all waves done reading XT; region A becomes VT
#pragma unroll
      for (int n = 0; n < 4; ++n) {
        int o = wcol + n * 16 + l15;
        float bv = bias[o];
        int dd = o & 63;
#pragma unroll
        for (int m = 0; m < 4; ++m)
#pragma unroll
          for (int r = 0; r < 4; ++r) {
            int t = m * 16 + ig + r;
            if (t < 49) {
              int s = t * 8 + (o >> 6);
              int h2 = (s * 1339) >> 16;       // s / 49
              int tp = s - h2 * 49;
              *(unsigned short*)(sm + h2 * 7168 + dd * 112 + tp * 2) = f2bf(acc[m][n][r] + bv);
            }
          }
      }
      // zero VT pads t' = 49..55 (read by PV B-fragments)
      {
        int h2 = tid >> 6, dd = tid & 63;
        char* p = sm + h2 * 7168 + dd * 112;
#pragma unroll
        for (int q = 49; q < 56; ++q) *(unsigned short*)(p + q * 2) = 0;
      }
      __syncthreads();
    }
  }

  // ---- attention: wave = head h ----
  const int h = wave;
  const float* bias_f = (const float*)(sm + LDS_BIAS);

  float4v sc[4][4];
#pragma unroll
  for (int m = 0; m < 4; ++m)
#pragma unroll
    for (int n = 0; n < 4; ++n) sc[m][n] = (float4v)0.f;

  for (int ks = 0; ks < 2; ++ks) {
    const int dd = ks * 32 + l4 * 8;
    bf16x8 a[4], b[4];
#pragma unroll
    for (int m = 0; m < 4; ++m) {
      int tp = m * 16 + l15;
      if (tp < 49) {
        int s = h * 49 + tp;
        int flat = s * 128 + dd * 2;
        a[m] = __builtin_bit_cast(bf16x8, *(const short8*)(sm + LDS_PQ + (flat ^ ((s & 7) << 4))));
      } else {
        a[m] = __builtin_bit_cast(bf16x8, (short8)0);
      }
    }
#pragma unroll
    for (int n = 0; n < 4; ++n) {
      int tp = n * 16 + l15;
      if (tp < 49) {
        int s = h * 49 + tp;
        int flat = s * 128 + dd * 2;
        b[n] = __builtin_bit_cast(bf16x8, *(const short8*)(sm + LDS_PK + (flat ^ ((s & 7) << 4))));
      } else {
        b[n] = __builtin_bit_cast(bf16x8, (short8)0);
      }
    }
#pragma unroll
    for (int m = 0; m < 4; ++m)
#pragma unroll
      for (int n = 0; n < 4; ++n)
        sc[m][n] = __builtin_amdgcn_mfma_f32_16x16x32_bf16(a[m], b[n], sc[m][n], 0, 0, 0);
  }

  // softmax (rows i across 16 lanes of same l4 group + 4 n-tiles in-register)
#pragma unroll
  for (int m = 0; m < 4; ++m)
#pragma unroll
    for (int r = 0; r < 4; ++r) {
      int i = m * 16 + ig + r;
      int yi = (i * 37) >> 8, xi = i - yi * 7;
      float rowv[4];
      float mx = -1e30f;
#pragma unroll
      for (int n = 0; n < 4; ++n) {
        int j = n * 16 + l15;
        float v = -1e30f;
        if (i < 49 && j < 49) {
          int yj = (j * 37) >> 8, xj = j - yj * 7;
          int idx = (yi - yj + 6) * 13 + (xi - xj + 6);
          v = sc[m][n][r] * 0.125f + bias_f[idx * 8 + h];
        }
        rowv[n] = v;
        mx = fmaxf(mx, v);
      }
      mx = fmaxf(mx, __shfl_xor(mx, 1));
      mx = fmaxf(mx, __shfl_xor(mx, 2));
      mx = fmaxf(mx, __shfl_xor(mx, 4));
      mx = fmaxf(mx, __shfl_xor(mx, 8));
      float ssum = 0.f;
#pragma unroll
      for (int n = 0; n < 4; ++n) {
        float e = (rowv[n] > -1e29f) ? __expf(rowv[n] - mx) : 0.f;
        rowv[n] = e;
        ssum += e;
      }
      ssum += __shfl_xor(ssum, 1);
      ssum += __shfl_xor(ssum, 2);
      ssum += __shfl_xor(ssum, 4);
      ssum += __shfl_xor(ssum, 8);
      float inv = 1.f / ssum;
#pragma unroll
      for (int n = 0; n < 4; ++n) sc[m][n][r] = rowv[n] * inv;
    }

  __syncthreads();  // Pq/Pk dead for ALL waves -> overlay attn
  const int ovb = LDS_PQ + wave * 8192;  // [64][64] bf16, row-XOR swizzled
#pragma unroll
  for (int m = 0; m < 4; ++m)
#pragma unroll
    for (int r = 0; r < 4; ++r) {
      int i = m * 16 + ig + r;
      if (i < 49) {
        int rowbase = i * 128;
        int swz = (i & 7) << 4;
#pragma unroll
        for (int n = 0; n < 4; ++n) {
          int j = n * 16 + l15;
          *(unsigned short*)(sm + ovb + ((rowbase + j * 2) ^ swz)) = f2bf(sc[m][n][r]);
        }
      }
    }
  __syncthreads();

  // PV: out = attn @ V  (B-fragments from VT[h][dd][t'])
  float4v oacc[4][4];
#pragma unroll
  for (int m = 0; m < 4; ++m)
#pragma unroll
    for (int n = 0; n < 4; ++n) oacc[m][n] = (float4v)0.f;

  for (int ks = 0; ks < 2; ++ks) {
    const int tp0 = ks * 32 + l4 * 8;
    bf16x8 a[4], b[4];
#pragma unroll
    for (int m = 0; m < 4; ++m) {
      int i = m * 16 + l15;
      int flat = i * 128 + tp0 * 2;
      a[m] = __builtin_bit_cast(bf16x8, *(const short8*)(sm + ovb + (flat ^ ((i & 7) << 4))));
    }
    const int tt = (tp0 >= 56) ? 0 : tp0;  // clamp: attn cols >=49 are zero anyway
#pragma unroll
    for (int n = 0; n < 4; ++n) {
      int dd = n * 16 + l15;
      b[n] = __builtin_bit_cast(bf16x8, *(const short8*)(sm + h * 7168 + dd * 112 + tt * 2));
    }
#pragma unroll
    for (int m = 0; m < 4; ++m)
#pragma unroll
      for (int n = 0; n < 4; ++n)
        oacc[m][n] = __builtin_amdgcn_mfma_f32_16x16x32_bf16(a[m], b[n], oacc[m][n], 0, 0, 0);
  }

  // output: flat [b][wi][h][t'][dd]
  float* op = out + (size_t)bwi * 25088 + h * 3136;
#pragma unroll
  for (int m = 0; m < 4; ++m)
#pragma unroll
    for (int r = 0; r < 4; ++r) {
      int tp = m * 16 + ig + r;
      if (tp < 49) {
#pragma unroll
        for (int n = 0; n < 4; ++n)
          op[tp * 64 + n * 16 + l15] = oacc[m][n][r];
      }
    }
}

extern "C" void kernel_launch(void* const* d_in, const int* in_sizes, int n_in,
                              void* d_out, int out_size, void* d_ws, size_t ws_size,
                              hipStream_t stream) {
  const float* x    = (const float*)d_in[0];
  const float* q_w  = (const float*)d_in[1];
  const float* q_b  = (const float*)d_in[2];
  const float* k_w  = (const float*)d_in[3];
  const float* k_b  = (const float*)d_in[4];
  const float* v_w  = (const float*)d_in[5];
  const float* v_b  = (const float*)d_in[6];
  const float* btab = (const float*)d_in[7];
  short* wcvt = (short*)d_ws;  // 3 * 512 * 512 bf16 = 1.5 MB

  hipLaunchKernelGGL(wconv_kernel, dim3(768), dim3(256), 0, stream, q_w, k_w, v_w, wcvt);
  hipLaunchKernelGGL(wattn_kernel, dim3(1024), dim3(512), 0, stream,
                     x, wcvt, q_b, k_b, v_b, btab, (float*)d_out);
}